// Round 1
// baseline (238.396 us; speedup 1.0000x reference)
//
#include <hip/hip_runtime.h>
#include <stdint.h>

#define S_LEN 2048
#define NHEADS 16
#define DHEAD 64
#define DMODEL 1024

typedef unsigned short u16;
typedef unsigned int u32;
typedef __bf16 bf16x8 __attribute__((ext_vector_type(8)));
typedef float f32x4 __attribute__((ext_vector_type(4)));

__device__ __forceinline__ float bf2f(u16 u) {
  u32 x = ((u32)u) << 16;
  float f;
  __builtin_memcpy(&f, &x, 4);
  return f;
}
__device__ __forceinline__ u16 f2bf(float f) {
  u32 x;
  __builtin_memcpy(&x, &f, 4);
  x += 0x7FFFu + ((x >> 16) & 1u);
  return (u16)(x >> 16);
}

#define AS1 __attribute__((address_space(1)))
#define AS3 __attribute__((address_space(3)))
// async global->LDS, 16B per lane; LDS dest is wave-uniform base + lane*16
__device__ __forceinline__ void gload16(const void* g, void* l) {
  __builtin_amdgcn_global_load_lds((AS1 void*)g, (AS3 void*)l, 16, 0, 0);
}

// ---------------- f32 -> bf16 convert: x (4 parts of 1M) + 4 weight mats ----
__global__ __launch_bounds__(256) void convert_k(
    const float* __restrict__ x, const float* __restrict__ wq, const float* __restrict__ wk,
    const float* __restrict__ wv, const float* __restrict__ wo,
    u16* __restrict__ xb, u16* __restrict__ wqb, u16* __restrict__ wkb,
    u16* __restrict__ wvb, u16* __restrict__ wob) {
  int part = blockIdx.y;
  const float* src;
  u16* dst;
  size_t base = 0;
  if (part < 4) { src = x; dst = xb; base = (size_t)part << 20; }
  else if (part == 4) { src = wq; dst = wqb; }
  else if (part == 5) { src = wk; dst = wkb; }
  else if (part == 6) { src = wv; dst = wvb; }
  else { src = wo; dst = wob; }
  size_t i = base + ((size_t)(blockIdx.x * 256 + threadIdx.x)) * 4;
  float4 v = *(const float4*)(src + i);
  ushort4 o;
  o.x = f2bf(v.x); o.y = f2bf(v.y); o.z = f2bf(v.z); o.w = f2bf(v.w);
  *(ushort4*)(dst + i) = o;
}

// ---------------- 128x128 bf16 GEMM, C = A * B^T (A:[M][K], B:[N][K]) ------
// MODE 0: write f32 row-major [M][N].  MODE 1: write bf16 to [B,H,S,DK].
template <int MODE>
__global__ __launch_bounds__(256) void gemm128(
    const u16* __restrict__ A, const u16* __restrict__ B0, const u16* __restrict__ B1,
    const u16* __restrict__ B2, void* __restrict__ O0, void* __restrict__ O1,
    void* __restrict__ O2) {
  __shared__ alignas(16) u16 As[128 * 64];
  __shared__ alignas(16) u16 Bs[128 * 64];
  int z = blockIdx.z;
  const u16* Bm = (z == 0) ? B0 : ((z == 1) ? B1 : B2);
  void* Om = (z == 0) ? O0 : ((z == 1) ? O1 : O2);
  int m0 = blockIdx.x * 128, n0 = blockIdx.y * 128;
  int t = threadIdx.x;
  int w = t >> 6, lane = t & 63, lr = lane >> 4, lc = lane & 15;
  int wr = w >> 1, wc = w & 1;
  f32x4 acc[4][4] = {};
  int srow = t >> 3;
  int scolb = (t & 7) * 16;
  const char* Ag = (const char*)A;
  const char* Bg = (const char*)Bm;
  for (int k0 = 0; k0 < DMODEL; k0 += 64) {
#pragma unroll
    for (int i = 0; i < 4; i++) {
      gload16(Ag + ((size_t)(m0 + srow + i * 32) * DMODEL + k0) * 2 + scolb,
              (char*)As + i * 4096 + w * 1024);
      gload16(Bg + ((size_t)(n0 + srow + i * 32) * DMODEL + k0) * 2 + scolb,
              (char*)Bs + i * 4096 + w * 1024);
    }
    __syncthreads();
#pragma unroll
    for (int kk = 0; kk < 2; kk++) {
      bf16x8 af[4], bfr[4];
#pragma unroll
      for (int mi = 0; mi < 4; mi++)
        af[mi] = *(const bf16x8*)(As + (wr * 64 + mi * 16 + lc) * 64 + kk * 32 + lr * 8);
#pragma unroll
      for (int ni = 0; ni < 4; ni++)
        bfr[ni] = *(const bf16x8*)(Bs + (wc * 64 + ni * 16 + lc) * 64 + kk * 32 + lr * 8);
#pragma unroll
      for (int mi = 0; mi < 4; mi++)
#pragma unroll
        for (int ni = 0; ni < 4; ni++)
          acc[mi][ni] =
              __builtin_amdgcn_mfma_f32_16x16x32_bf16(af[mi], bfr[ni], acc[mi][ni], 0, 0, 0);
    }
    __syncthreads();
  }
  if (MODE == 0) {
    float* Of = (float*)Om;
#pragma unroll
    for (int mi = 0; mi < 4; mi++)
#pragma unroll
      for (int ni = 0; ni < 4; ni++) {
        int m = m0 + wr * 64 + mi * 16 + lr * 4;
        int n = n0 + wc * 64 + ni * 16 + lc;
#pragma unroll
        for (int r = 0; r < 4; r++) Of[(size_t)(m + r) * DMODEL + n] = acc[mi][ni][r];
      }
  } else {
    u16* Oh = (u16*)Om;
#pragma unroll
    for (int mi = 0; mi < 4; mi++)
#pragma unroll
      for (int ni = 0; ni < 4; ni++) {
        int n = n0 + wc * 64 + ni * 16 + lc;
        int h = n >> 6, d = n & 63;
#pragma unroll
        for (int r = 0; r < 4; r++) {
          int m = m0 + wr * 64 + mi * 16 + lr * 4 + r;
          int b = m >> 11, s = m & 2047;
          Oh[((size_t)(b * NHEADS + h) * S_LEN + s) * DHEAD + d] = f2bf(acc[mi][ni][r]);
        }
      }
  }
}

// ---------------- RoPE in-place on bf16 Q (y=0, with 1/8 scale) and K (y=1) -
__global__ __launch_bounds__(256) void rope_k(u16* __restrict__ Q, u16* __restrict__ K,
                                              const int* __restrict__ pos) {
  int sel = blockIdx.y;
  u16* Aq = sel ? K : Q;
  float oscale = sel ? 1.0f : 0.125f;  // fold 1/sqrt(DK) into Q (exact pow2 in bf16)
  int idx = blockIdx.x * 256 + threadIdx.x;  // 0..262143 (B*H*S*4)
  int r = idx >> 2, seg = idx & 3;
  int b = r >> 15, s = r & 2047;
  float p = (float)pos[(b << 11) + s];
  u16* ptr = Aq + (size_t)r * DHEAD + seg * 16;
  alignas(16) u16 e[16];
  *(uint4*)&e[0] = *(const uint4*)ptr;
  *(uint4*)&e[8] = *(const uint4*)(ptr + 8);
#pragma unroll
  for (int j = 0; j < 8; j++) {
    int i = seg * 8 + j;  // pair index 0..31
    float fr = exp2f(-0.4152410118407687f * (float)i);  // theta^(-2i/64)
    float ang = p * fr;
    float sn, cs;
    __sincosf(ang, &sn, &cs);
    float ev = bf2f(e[2 * j]), ov = bf2f(e[2 * j + 1]);
    e[2 * j] = f2bf((ev * cs - ov * sn) * oscale);
    e[2 * j + 1] = f2bf((ev * sn + ov * cs) * oscale);
  }
  *(uint4*)ptr = *(const uint4*)&e[0];
  *(uint4*)(ptr + 8) = *(const uint4*)&e[8];
}

// ---------------- V [B,H,S,DK] -> VT [B,H,DK,S] -----------------------------
__global__ __launch_bounds__(256) void transpose_v(const u16* __restrict__ V,
                                                   u16* __restrict__ VT) {
  __shared__ alignas(16) u16 T[64][72];
  int kv0 = blockIdx.x * 64;
  int bh = blockIdx.y;
  int t = threadIdx.x;
  int rr = t >> 3, c8 = (t & 7) * 8;
  const u16* src = V + ((size_t)bh * S_LEN + kv0) * DHEAD;
#pragma unroll
  for (int i = 0; i < 2; i++) {
    const u16* sp = src + (size_t)(rr + i * 32) * DHEAD + c8;
    *(uint2*)&T[rr + i * 32][c8] = *(const uint2*)sp;
    *(uint2*)&T[rr + i * 32][c8 + 4] = *(const uint2*)(sp + 4);
  }
  __syncthreads();
  u16* dst = VT + (size_t)bh * DHEAD * S_LEN + kv0;
#pragma unroll
  for (int i = 0; i < 2; i++) {
    int d = rr + i * 32;
    ushort4 a, c;
    a.x = T[c8 + 0][d]; a.y = T[c8 + 1][d]; a.z = T[c8 + 2][d]; a.w = T[c8 + 3][d];
    c.x = T[c8 + 4][d]; c.y = T[c8 + 5][d]; c.z = T[c8 + 6][d]; c.w = T[c8 + 7][d];
    *(ushort4*)(dst + (size_t)d * S_LEN + c8) = a;
    *(ushort4*)(dst + (size_t)d * S_LEN + c8 + 4) = c;
  }
}

// ---------------- causal flash attention, 64 q-rows/block, 4 waves ----------
__global__ __launch_bounds__(256) void attn_k(const u16* __restrict__ Q,
                                              const u16* __restrict__ K,
                                              const u16* __restrict__ VT,
                                              u16* __restrict__ O) {
  __shared__ alignas(16) u16 Ks[64 * 64];
  __shared__ alignas(16) u16 Vs[64 * 64];           // holds VT tile: [d][kv]
  __shared__ alignas(16) u16 Ps[4][16 * 88];        // per-wave P, stride 88 (176B, 16B-mult)
  int qt = (int)gridDim.x - 1 - (int)blockIdx.x;    // heavy blocks first
  int bh = blockIdx.y;
  int t = threadIdx.x, w = t >> 6, lane = t & 63, lr = lane >> 4, lc = lane & 15;
  size_t base = (size_t)bh * S_LEN * DHEAD;
  int q0 = qt * 64 + w * 16;
  bf16x8 qf0 = *(const bf16x8*)(Q + base + (size_t)(q0 + lc) * DHEAD + lr * 8);
  bf16x8 qf1 = *(const bf16x8*)(Q + base + (size_t)(q0 + lc) * DHEAD + 32 + lr * 8);
  f32x4 acc[4] = {};
  float mrun[4], lrun[4];
#pragma unroll
  for (int r = 0; r < 4; r++) { mrun[r] = -1e30f; lrun[r] = 0.0f; }
  int srow = t >> 3, scolb = (t & 7) * 16;
  for (int nt = 0; nt <= qt; nt++) {
    int kv0 = nt * 64;
#pragma unroll
    for (int i = 0; i < 2; i++) {
      gload16((const char*)K + (base + (size_t)(kv0 + srow + i * 32) * DHEAD) * 2 + scolb,
              (char*)Ks + i * 4096 + w * 1024);
      gload16((const char*)VT + (base + (size_t)(srow + i * 32) * S_LEN + kv0) * 2 + scolb,
              (char*)Vs + i * 4096 + w * 1024);
    }
    __syncthreads();
    // S = Q K^T  (rows q: (lr*4+r), cols kv: n4*16+lc)
    f32x4 sv[4];
#pragma unroll
    for (int n4 = 0; n4 < 4; n4++) {
      f32x4 a = {0.0f, 0.0f, 0.0f, 0.0f};
      bf16x8 k0 = *(const bf16x8*)(Ks + (n4 * 16 + lc) * 64 + lr * 8);
      bf16x8 k1 = *(const bf16x8*)(Ks + (n4 * 16 + lc) * 64 + 32 + lr * 8);
      a = __builtin_amdgcn_mfma_f32_16x16x32_bf16(qf0, k0, a, 0, 0, 0);
      a = __builtin_amdgcn_mfma_f32_16x16x32_bf16(qf1, k1, a, 0, 0, 0);
      sv[n4] = a;
    }
    if (nt == qt) {  // diagonal tile: causal mask
#pragma unroll
      for (int n4 = 0; n4 < 4; n4++)
#pragma unroll
        for (int r = 0; r < 4; r++)
          if (kv0 + n4 * 16 + lc > q0 + lr * 4 + r) sv[n4][r] = -1e30f;
    }
    // online softmax (row reductions across the 16 col-lanes)
    float scl[4];
#pragma unroll
    for (int r = 0; r < 4; r++) {
      float v = fmaxf(fmaxf(sv[0][r], sv[1][r]), fmaxf(sv[2][r], sv[3][r]));
      v = fmaxf(v, __shfl_xor(v, 1));
      v = fmaxf(v, __shfl_xor(v, 2));
      v = fmaxf(v, __shfl_xor(v, 4));
      v = fmaxf(v, __shfl_xor(v, 8));
      float mn = fmaxf(mrun[r], v);
      scl[r] = __expf(mrun[r] - mn);
      mrun[r] = mn;
    }
#pragma unroll
    for (int n4 = 0; n4 < 4; n4++)
#pragma unroll
      for (int r = 0; r < 4; r++) sv[n4][r] = __expf(sv[n4][r] - mrun[r]);
#pragma unroll
    for (int r = 0; r < 4; r++) {
      float v = sv[0][r] + sv[1][r] + sv[2][r] + sv[3][r];
      v += __shfl_xor(v, 1);
      v += __shfl_xor(v, 2);
      v += __shfl_xor(v, 4);
      v += __shfl_xor(v, 8);
      lrun[r] = lrun[r] * scl[r] + v;
#pragma unroll
      for (int dt = 0; dt < 4; dt++) acc[dt][r] *= scl[r];
    }
    // P -> LDS (bf16), re-read in A-frag layout
    u16* pw = &Ps[w][0];
#pragma unroll
    for (int n4 = 0; n4 < 4; n4++)
#pragma unroll
      for (int r = 0; r < 4; r++)
        pw[(lr * 4 + r) * 88 + n4 * 16 + lc] = f2bf(sv[n4][r]);
    asm volatile("s_waitcnt lgkmcnt(0)" ::: "memory");
    bf16x8 p0 = *(const bf16x8*)(pw + lc * 88 + lr * 8);
    bf16x8 p1 = *(const bf16x8*)(pw + lc * 88 + 32 + lr * 8);
#pragma unroll
    for (int dt = 0; dt < 4; dt++) {
      bf16x8 v0 = *(const bf16x8*)(Vs + (dt * 16 + lc) * 64 + lr * 8);
      bf16x8 v1 = *(const bf16x8*)(Vs + (dt * 16 + lc) * 64 + 32 + lr * 8);
      acc[dt] = __builtin_amdgcn_mfma_f32_16x16x32_bf16(p0, v0, acc[dt], 0, 0, 0);
      acc[dt] = __builtin_amdgcn_mfma_f32_16x16x32_bf16(p1, v1, acc[dt], 0, 0, 0);
    }
    __syncthreads();
  }
  int b = bh >> 4, h = bh & 15;
#pragma unroll
  for (int r = 0; r < 4; r++) {
    int qi = q0 + lr * 4 + r;
    float inv = 1.0f / lrun[r];
#pragma unroll
    for (int dt = 0; dt < 4; dt++)
      O[((size_t)(b * S_LEN + qi)) * DMODEL + h * DHEAD + dt * 16 + lc] =
          f2bf(acc[dt][r] * inv);
  }
}

// ---------------- launch -----------------------------------------------------
extern "C" void kernel_launch(void* const* d_in, const int* in_sizes, int n_in,
                              void* d_out, int out_size, void* d_ws, size_t ws_size,
                              hipStream_t stream) {
  (void)in_sizes; (void)n_in; (void)out_size; (void)ws_size;
  const float* x = (const float*)d_in[0];
  const int* tpos = (const int*)d_in[1];
  const float* Wq = (const float*)d_in[2];
  const float* Wk = (const float*)d_in[3];
  const float* Wv = (const float*)d_in[4];
  const float* Wo = (const float*)d_in[5];
  char* ws = (char*)d_ws;
  // workspace map (56 MB total)
  u16* xb  = (u16*)(ws + ((size_t)0 << 20));   // 8 MB  [4096][1024] bf16
  u16* wqb = (u16*)(ws + ((size_t)8 << 20));   // 2 MB
  u16* wkb = (u16*)(ws + ((size_t)10 << 20));  // 2 MB
  u16* wvb = (u16*)(ws + ((size_t)12 << 20));  // 2 MB
  u16* wob = (u16*)(ws + ((size_t)14 << 20));  // 2 MB
  u16* Qb  = (u16*)(ws + ((size_t)16 << 20));  // 8 MB  [B,H,S,DK]
  u16* Kb  = (u16*)(ws + ((size_t)24 << 20));  // 8 MB
  u16* Vb  = (u16*)(ws + ((size_t)32 << 20));  // 8 MB
  u16* VTb = (u16*)(ws + ((size_t)40 << 20));  // 8 MB  [B,H,DK,S]
  u16* Ob  = (u16*)(ws + ((size_t)48 << 20));  // 8 MB  [B,S,DMODEL] bf16

  convert_k<<<dim3(1024, 8), 256, 0, stream>>>(x, Wq, Wk, Wv, Wo, xb, wqb, wkb, wvb, wob);
  gemm128<1><<<dim3(32, 8, 3), 256, 0, stream>>>(xb, wqb, wkb, wvb,
                                                 (void*)Qb, (void*)Kb, (void*)Vb);
  rope_k<<<dim3(1024, 2), 256, 0, stream>>>(Qb, Kb, tpos);
  transpose_v<<<dim3(32, 32), 256, 0, stream>>>(Vb, VTb);
  attn_k<<<dim3(32, 32), 256, 0, stream>>>(Qb, Kb, VTb, Ob);
  gemm128<0><<<dim3(32, 8, 1), 256, 0, stream>>>(Ob, wob, wob, wob, d_out, d_out, d_out);
}

// Round 2
// 158.990 us; speedup vs baseline: 1.4994x; 1.4994x over previous
//
#include <hip/hip_runtime.h>
#include <stdint.h>

#define S_LEN 2048
#define NHEADS 16
#define DHEAD 64
#define DMODEL 1024

typedef unsigned short u16;
typedef unsigned int u32;
typedef __bf16 bf16x8 __attribute__((ext_vector_type(8)));
typedef float f32x4 __attribute__((ext_vector_type(4)));

__device__ __forceinline__ float bf2f(u16 u) {
  u32 x = ((u32)u) << 16;
  float f;
  __builtin_memcpy(&f, &x, 4);
  return f;
}
__device__ __forceinline__ u16 f2bf(float f) {
  u32 x;
  __builtin_memcpy(&x, &f, 4);
  x += 0x7FFFu + ((x >> 16) & 1u);
  return (u16)(x >> 16);
}

#define AS1 __attribute__((address_space(1)))
#define AS3 __attribute__((address_space(3)))
// async global->LDS, 16B per lane; LDS dest is wave-uniform base + lane*16
__device__ __forceinline__ void gload16(const void* g, void* l) {
  __builtin_amdgcn_global_load_lds((AS1 void*)g, (AS3 void*)l, 16, 0, 0);
}

// ---------------- f32 -> bf16 convert: x (4 parts of 1M) + 4 weight mats ----
__global__ __launch_bounds__(256) void convert_k(
    const float* __restrict__ x, const float* __restrict__ wq, const float* __restrict__ wk,
    const float* __restrict__ wv, const float* __restrict__ wo,
    u16* __restrict__ xb, u16* __restrict__ wqb, u16* __restrict__ wkb,
    u16* __restrict__ wvb, u16* __restrict__ wob) {
  int part = blockIdx.y;
  const float* src;
  u16* dst;
  size_t base = 0;
  if (part < 4) { src = x; dst = xb; base = (size_t)part << 20; }
  else if (part == 4) { src = wq; dst = wqb; }
  else if (part == 5) { src = wk; dst = wkb; }
  else if (part == 6) { src = wv; dst = wvb; }
  else { src = wo; dst = wob; }
  size_t i = base + ((size_t)(blockIdx.x * 256 + threadIdx.x)) * 4;
  float4 v = *(const float4*)(src + i);
  ushort4 o;
  o.x = f2bf(v.x); o.y = f2bf(v.y); o.z = f2bf(v.z); o.w = f2bf(v.w);
  *(ushort4*)(dst + i) = o;
}

// ---------------- 128x128 bf16 GEMM, C = A * B^T (A:[M][K], B:[N][K]) ------
// MODE 0: write f32 row-major [M][N].  MODE 1: write bf16 to [B,H,S,DK].
template <int MODE>
__global__ __launch_bounds__(256) void gemm128(
    const u16* __restrict__ A, const u16* __restrict__ B0, const u16* __restrict__ B1,
    const u16* __restrict__ B2, void* __restrict__ O0, void* __restrict__ O1,
    void* __restrict__ O2) {
  __shared__ alignas(16) u16 As[128 * 64];
  __shared__ alignas(16) u16 Bs[128 * 64];
  int z = blockIdx.z;
  const u16* Bm = (z == 0) ? B0 : ((z == 1) ? B1 : B2);
  void* Om = (z == 0) ? O0 : ((z == 1) ? O1 : O2);
  int m0 = blockIdx.x * 128, n0 = blockIdx.y * 128;
  int t = threadIdx.x;
  int w = t >> 6, lane = t & 63, lr = lane >> 4, lc = lane & 15;
  int wr = w >> 1, wc = w & 1;
  f32x4 acc[4][4] = {};
  int srow = t >> 3;
  int scolb = (t & 7) * 16;
  const char* Ag = (const char*)A;
  const char* Bg = (const char*)Bm;
  for (int k0 = 0; k0 < DMODEL; k0 += 64) {
#pragma unroll
    for (int i = 0; i < 4; i++) {
      gload16(Ag + ((size_t)(m0 + srow + i * 32) * DMODEL + k0) * 2 + scolb,
              (char*)As + i * 4096 + w * 1024);
      gload16(Bg + ((size_t)(n0 + srow + i * 32) * DMODEL + k0) * 2 + scolb,
              (char*)Bs + i * 4096 + w * 1024);
    }
    __syncthreads();
#pragma unroll
    for (int kk = 0; kk < 2; kk++) {
      bf16x8 af[4], bfr[4];
#pragma unroll
      for (int mi = 0; mi < 4; mi++)
        af[mi] = *(const bf16x8*)(As + (wr * 64 + mi * 16 + lc) * 64 + kk * 32 + lr * 8);
#pragma unroll
      for (int ni = 0; ni < 4; ni++)
        bfr[ni] = *(const bf16x8*)(Bs + (wc * 64 + ni * 16 + lc) * 64 + kk * 32 + lr * 8);
#pragma unroll
      for (int mi = 0; mi < 4; mi++)
#pragma unroll
        for (int ni = 0; ni < 4; ni++)
          acc[mi][ni] =
              __builtin_amdgcn_mfma_f32_16x16x32_bf16(af[mi], bfr[ni], acc[mi][ni], 0, 0, 0);
    }
    __syncthreads();
  }
  if (MODE == 0) {
    float* Of = (float*)Om;
#pragma unroll
    for (int mi = 0; mi < 4; mi++)
#pragma unroll
      for (int ni = 0; ni < 4; ni++) {
        int m = m0 + wr * 64 + mi * 16 + lr * 4;
        int n = n0 + wc * 64 + ni * 16 + lc;
#pragma unroll
        for (int r = 0; r < 4; r++) Of[(size_t)(m + r) * DMODEL + n] = acc[mi][ni][r];
      }
  } else {
    u16* Oh = (u16*)Om;
#pragma unroll
    for (int mi = 0; mi < 4; mi++)
#pragma unroll
      for (int ni = 0; ni < 4; ni++) {
        int n = n0 + wc * 64 + ni * 16 + lc;
        int h = n >> 6, d = n & 63;
#pragma unroll
        for (int r = 0; r < 4; r++) {
          int m = m0 + wr * 64 + mi * 16 + lr * 4 + r;
          int b = m >> 11, s = m & 2047;
          Oh[((size_t)(b * NHEADS + h) * S_LEN + s) * DHEAD + d] = f2bf(acc[mi][ni][r]);
        }
      }
  }
}

// ---------------- RoPE in-place on bf16 Q (y=0, with 1/8 scale) and K (y=1) -
__global__ __launch_bounds__(256) void rope_k(u16* __restrict__ Q, u16* __restrict__ K,
                                              const int* __restrict__ pos) {
  int sel = blockIdx.y;
  u16* Aq = sel ? K : Q;
  float oscale = sel ? 1.0f : 0.125f;  // fold 1/sqrt(DK) into Q (exact pow2 in bf16)
  int idx = blockIdx.x * 256 + threadIdx.x;  // 0..262143 (B*H*S*4)
  int r = idx >> 2, seg = idx & 3;
  int b = r >> 15, s = r & 2047;
  float p = (float)pos[(b << 11) + s];
  u16* ptr = Aq + (size_t)r * DHEAD + seg * 16;
  alignas(16) u16 e[16];
  *(uint4*)&e[0] = *(const uint4*)ptr;
  *(uint4*)&e[8] = *(const uint4*)(ptr + 8);
#pragma unroll
  for (int j = 0; j < 8; j++) {
    int i = seg * 8 + j;  // pair index 0..31
    float fr = exp2f(-0.4152410118407687f * (float)i);  // theta^(-2i/64)
    float ang = p * fr;
    float sn, cs;
    __sincosf(ang, &sn, &cs);
    float ev = bf2f(e[2 * j]), ov = bf2f(e[2 * j + 1]);
    e[2 * j] = f2bf((ev * cs - ov * sn) * oscale);
    e[2 * j + 1] = f2bf((ev * sn + ov * cs) * oscale);
  }
  *(uint4*)ptr = *(const uint4*)&e[0];
  *(uint4*)(ptr + 8) = *(const uint4*)&e[8];
}

// ---------------- V [B,H,S,DK] -> VT [B,H,DK,S] -----------------------------
__global__ __launch_bounds__(256) void transpose_v(const u16* __restrict__ V,
                                                   u16* __restrict__ VT) {
  __shared__ alignas(16) u16 T[64][72];
  int kv0 = blockIdx.x * 64;
  int bh = blockIdx.y;
  int t = threadIdx.x;
  int rr = t >> 3, c8 = (t & 7) * 8;
  const u16* src = V + ((size_t)bh * S_LEN + kv0) * DHEAD;
#pragma unroll
  for (int i = 0; i < 2; i++) {
    const u16* sp = src + (size_t)(rr + i * 32) * DHEAD + c8;
    *(uint2*)&T[rr + i * 32][c8] = *(const uint2*)sp;
    *(uint2*)&T[rr + i * 32][c8 + 4] = *(const uint2*)(sp + 4);
  }
  __syncthreads();
  u16* dst = VT + (size_t)bh * DHEAD * S_LEN + kv0;
#pragma unroll
  for (int i = 0; i < 2; i++) {
    int d = rr + i * 32;
    ushort4 a, c;
    a.x = T[c8 + 0][d]; a.y = T[c8 + 1][d]; a.z = T[c8 + 2][d]; a.w = T[c8 + 3][d];
    c.x = T[c8 + 4][d]; c.y = T[c8 + 5][d]; c.z = T[c8 + 6][d]; c.w = T[c8 + 7][d];
    *(ushort4*)(dst + (size_t)d * S_LEN + c8) = a;
    *(ushort4*)(dst + (size_t)d * S_LEN + c8 + 4) = c;
  }
}

// ---------------- causal flash attention, 64 q-rows/block, 4 waves ----------
// v2: XOR-swizzled K/V LDS (kills 16-way b128 conflict), double-buffered
// 2-phase pipeline with raw s_barrier + explicit vmcnt, setprio on MFMA,
// bh-major grid (bh%8 pins XCD; heavy q-tiles dispatched first).
__global__ __launch_bounds__(256) void attn_k(const u16* __restrict__ Q,
                                              const u16* __restrict__ K,
                                              const u16* __restrict__ VT,
                                              u16* __restrict__ O) {
  __shared__ alignas(16) u16 Ks[2][64 * 64];
  __shared__ alignas(16) u16 Vs[2][64 * 64];        // holds VT tile: [d][kv]
  __shared__ alignas(16) u16 Ps[4][16 * 88];        // per-wave P, stride 88
  int bh = blockIdx.x;                              // bh fastest -> bh%8 = XCD
  int qt = 31 - (int)blockIdx.y;                    // heavy blocks first
  int t = threadIdx.x, w = t >> 6, lane = t & 63, lr = lane >> 4, lc = lane & 15;
  size_t base = (size_t)bh * S_LEN * DHEAD;
  int q0 = qt * 64 + w * 16;
  bf16x8 qf0 = *(const bf16x8*)(Q + base + (size_t)(q0 + lc) * DHEAD + lr * 8);
  bf16x8 qf1 = *(const bf16x8*)(Q + base + (size_t)(q0 + lc) * DHEAD + 32 + lr * 8);
  f32x4 acc[4] = {};
  float mrun[4], lrun[4];
#pragma unroll
  for (int r = 0; r < 4; r++) { mrun[r] = -1e30f; lrun[r] = 0.0f; }
  int srow = t >> 3;
  int swc = ((t & 7) ^ (srow & 7)) << 4;  // pre-swizzled source chunk (bytes)
  const char* Kg0 = (const char*)K + (base + (size_t)srow * DHEAD) * 2 + swc;
  const char* Vg0 = (const char*)VT + (base + (size_t)srow * S_LEN) * 2 + swc;
  char* klb = (char*)&Ks[0][0] + w * 1024;
  char* vlb = (char*)&Vs[0][0] + w * 1024;

#define STAGE(nt, buf)                                          \
  do {                                                          \
    size_t kvo = (size_t)(nt) * 64;                             \
    const char* kg = Kg0 + kvo * DHEAD * 2;                     \
    const char* vg = Vg0 + kvo * 2;                             \
    char* kl = klb + (buf) * 8192;                              \
    char* vl = vlb + (buf) * 8192;                              \
    gload16(kg, kl);                                            \
    gload16(kg + (size_t)32 * DHEAD * 2, kl + 4096);            \
    gload16(vg, vl);                                            \
    gload16(vg + (size_t)32 * S_LEN * 2, vl + 4096);            \
  } while (0)

  STAGE(0, 0);
  asm volatile("s_waitcnt vmcnt(0)" ::: "memory");
  __builtin_amdgcn_s_barrier();
  asm volatile("" ::: "memory");
  int cur = 0;
  for (int nt = 0; nt <= qt; nt++) {
    if (nt < qt) STAGE(nt + 1, cur ^ 1);  // issue next-tile loads (in flight over compute)
    const char* kb = (const char*)&Ks[cur][0];
    const char* vb = (const char*)&Vs[cur][0];
    int kv0 = nt * 64;
    // S = Q K^T  (rows q: lr*4+r, cols kv: n4*16+lc); swizzled chunk reads
    f32x4 sv[4];
    __builtin_amdgcn_s_setprio(1);
#pragma unroll
    for (int n4 = 0; n4 < 4; n4++) {
      int row = n4 * 16 + lc;
      f32x4 a = {0.0f, 0.0f, 0.0f, 0.0f};
      bf16x8 k0 = *(const bf16x8*)(kb + row * 128 + ((lr ^ (lc & 7)) << 4));
      bf16x8 k1 = *(const bf16x8*)(kb + row * 128 + (((4 + lr) ^ (lc & 7)) << 4));
      a = __builtin_amdgcn_mfma_f32_16x16x32_bf16(qf0, k0, a, 0, 0, 0);
      a = __builtin_amdgcn_mfma_f32_16x16x32_bf16(qf1, k1, a, 0, 0, 0);
      sv[n4] = a;
    }
    __builtin_amdgcn_s_setprio(0);
    if (nt == qt) {  // diagonal tile: causal mask
#pragma unroll
      for (int n4 = 0; n4 < 4; n4++)
#pragma unroll
        for (int r = 0; r < 4; r++)
          if (kv0 + n4 * 16 + lc > q0 + lr * 4 + r) sv[n4][r] = -1e30f;
    }
    // online softmax (row reductions across the 16 col-lanes)
    float scl[4];
#pragma unroll
    for (int r = 0; r < 4; r++) {
      float v = fmaxf(fmaxf(sv[0][r], sv[1][r]), fmaxf(sv[2][r], sv[3][r]));
      v = fmaxf(v, __shfl_xor(v, 1));
      v = fmaxf(v, __shfl_xor(v, 2));
      v = fmaxf(v, __shfl_xor(v, 4));
      v = fmaxf(v, __shfl_xor(v, 8));
      float mn = fmaxf(mrun[r], v);
      scl[r] = __expf(mrun[r] - mn);
      mrun[r] = mn;
    }
#pragma unroll
    for (int n4 = 0; n4 < 4; n4++)
#pragma unroll
      for (int r = 0; r < 4; r++) sv[n4][r] = __expf(sv[n4][r] - mrun[r]);
#pragma unroll
    for (int r = 0; r < 4; r++) {
      float v = sv[0][r] + sv[1][r] + sv[2][r] + sv[3][r];
      v += __shfl_xor(v, 1);
      v += __shfl_xor(v, 2);
      v += __shfl_xor(v, 4);
      v += __shfl_xor(v, 8);
      lrun[r] = lrun[r] * scl[r] + v;
#pragma unroll
      for (int dt = 0; dt < 4; dt++) acc[dt][r] *= scl[r];
    }
    // P -> LDS (bf16), re-read in A-frag layout
    u16* pw = &Ps[w][0];
#pragma unroll
    for (int n4 = 0; n4 < 4; n4++)
#pragma unroll
      for (int r = 0; r < 4; r++)
        pw[(lr * 4 + r) * 88 + n4 * 16 + lc] = f2bf(sv[n4][r]);
    asm volatile("s_waitcnt lgkmcnt(0)" ::: "memory");
    bf16x8 p0 = *(const bf16x8*)(pw + lc * 88 + lr * 8);
    bf16x8 p1 = *(const bf16x8*)(pw + lc * 88 + 32 + lr * 8);
    __builtin_amdgcn_s_setprio(1);
#pragma unroll
    for (int dt = 0; dt < 4; dt++) {
      int row = dt * 16 + lc;
      bf16x8 v0 = *(const bf16x8*)(vb + row * 128 + ((lr ^ (lc & 7)) << 4));
      bf16x8 v1 = *(const bf16x8*)(vb + row * 128 + (((4 + lr) ^ (lc & 7)) << 4));
      acc[dt] = __builtin_amdgcn_mfma_f32_16x16x32_bf16(p0, v0, acc[dt], 0, 0, 0);
      acc[dt] = __builtin_amdgcn_mfma_f32_16x16x32_bf16(p1, v1, acc[dt], 0, 0, 0);
    }
    __builtin_amdgcn_s_setprio(0);
    asm volatile("s_waitcnt vmcnt(0)" ::: "memory");  // next tile's loads landed
    __builtin_amdgcn_s_barrier();
    asm volatile("" ::: "memory");
    cur ^= 1;
  }
#undef STAGE
  int b = bh >> 4, h = bh & 15;
#pragma unroll
  for (int r = 0; r < 4; r++) {
    int qi = q0 + lr * 4 + r;
    float inv = 1.0f / lrun[r];
#pragma unroll
    for (int dt = 0; dt < 4; dt++)
      O[((size_t)(b * S_LEN + qi)) * DMODEL + h * DHEAD + dt * 16 + lc] =
          f2bf(acc[dt][r] * inv);
  }
}

// ---------------- launch -----------------------------------------------------
extern "C" void kernel_launch(void* const* d_in, const int* in_sizes, int n_in,
                              void* d_out, int out_size, void* d_ws, size_t ws_size,
                              hipStream_t stream) {
  (void)in_sizes; (void)n_in; (void)out_size; (void)ws_size;
  const float* x = (const float*)d_in[0];
  const int* tpos = (const int*)d_in[1];
  const float* Wq = (const float*)d_in[2];
  const float* Wk = (const float*)d_in[3];
  const float* Wv = (const float*)d_in[4];
  const float* Wo = (const float*)d_in[5];
  char* ws = (char*)d_ws;
  // workspace map (56 MB total)
  u16* xb  = (u16*)(ws + ((size_t)0 << 20));   // 8 MB  [4096][1024] bf16
  u16* wqb = (u16*)(ws + ((size_t)8 << 20));   // 2 MB
  u16* wkb = (u16*)(ws + ((size_t)10 << 20));  // 2 MB
  u16* wvb = (u16*)(ws + ((size_t)12 << 20));  // 2 MB
  u16* wob = (u16*)(ws + ((size_t)14 << 20));  // 2 MB
  u16* Qb  = (u16*)(ws + ((size_t)16 << 20));  // 8 MB  [B,H,S,DK]
  u16* Kb  = (u16*)(ws + ((size_t)24 << 20));  // 8 MB
  u16* Vb  = (u16*)(ws + ((size_t)32 << 20));  // 8 MB
  u16* VTb = (u16*)(ws + ((size_t)40 << 20));  // 8 MB  [B,H,DK,S]
  u16* Ob  = (u16*)(ws + ((size_t)48 << 20));  // 8 MB  [B,S,DMODEL] bf16

  convert_k<<<dim3(1024, 8), 256, 0, stream>>>(x, Wq, Wk, Wv, Wo, xb, wqb, wkb, wvb, wob);
  gemm128<1><<<dim3(32, 8, 3), 256, 0, stream>>>(xb, wqb, wkb, wvb,
                                                 (void*)Qb, (void*)Kb, (void*)Vb);
  rope_k<<<dim3(1024, 2), 256, 0, stream>>>(Qb, Kb, tpos);
  transpose_v<<<dim3(32, 32), 256, 0, stream>>>(Vb, VTb);
  attn_k<<<dim3(32, 32), 256, 0, stream>>>(Qb, Kb, VTb, Ob);
  gemm128<0><<<dim3(32, 8, 1), 256, 0, stream>>>(Ob, wob, wob, wob, d_out, d_out, d_out);
}

// Round 4
// 156.292 us; speedup vs baseline: 1.5253x; 1.0173x over previous
//
#include <hip/hip_runtime.h>
#include <stdint.h>

#define S_LEN 2048
#define NHEADS 16
#define DHEAD 64
#define DMODEL 1024

typedef unsigned short u16;
typedef unsigned int u32;
typedef __bf16 bf16x8 __attribute__((ext_vector_type(8)));
typedef float f32x4 __attribute__((ext_vector_type(4)));
typedef float f32x16 __attribute__((ext_vector_type(16)));
typedef u32 u32x4 __attribute__((ext_vector_type(4)));
typedef u32 u32x2 __attribute__((ext_vector_type(2)));

__device__ __forceinline__ float bf2f(u16 u) {
  u32 x = ((u32)u) << 16;
  float f;
  __builtin_memcpy(&f, &x, 4);
  return f;
}
__device__ __forceinline__ u16 f2bf(float f) {
  u32 x;
  __builtin_memcpy(&x, &f, 4);
  x += 0x7FFFu + ((x >> 16) & 1u);
  return (u16)(x >> 16);
}
// packed f32 pair -> bf16 pair (lo = a, hi = b)
__device__ __forceinline__ u32 cvtpk(float a, float b) {
  u32 r;
  asm("v_cvt_pk_bf16_f32 %0, %1, %2" : "=v"(r) : "v"(a), "v"(b));
  return r;
}
// r[0] = {a_lo, b_lo}, r[1] = {a_hi, b_hi}  (SSA builtin — no in-place asm hazard)
__device__ __forceinline__ u32x2 plswap2(u32 a, u32 b) {
  return __builtin_amdgcn_permlane32_swap(a, b, false, false);
}

#define AS1 __attribute__((address_space(1)))
#define AS3 __attribute__((address_space(3)))
// async global->LDS, 16B per lane; LDS dest is wave-uniform base + lane*16
__device__ __forceinline__ void gload16(const void* g, void* l) {
  __builtin_amdgcn_global_load_lds((AS1 void*)g, (AS3 void*)l, 16, 0, 0);
}

#define MFMA32(a, b, c) __builtin_amdgcn_mfma_f32_32x32x16_bf16(a, b, c, 0, 0, 0)

// ---------------- f32 -> bf16 convert: x (4 parts of 1M) + 4 weight mats ----
__global__ __launch_bounds__(256) void convert_k(
    const float* __restrict__ x, const float* __restrict__ wq, const float* __restrict__ wk,
    const float* __restrict__ wv, const float* __restrict__ wo,
    u16* __restrict__ xb, u16* __restrict__ wqb, u16* __restrict__ wkb,
    u16* __restrict__ wvb, u16* __restrict__ wob) {
  int part = blockIdx.y;
  const float* src;
  u16* dst;
  size_t base = 0;
  if (part < 4) { src = x; dst = xb; base = (size_t)part << 20; }
  else if (part == 4) { src = wq; dst = wqb; }
  else if (part == 5) { src = wk; dst = wkb; }
  else if (part == 6) { src = wv; dst = wvb; }
  else { src = wo; dst = wob; }
  size_t i = base + ((size_t)(blockIdx.x * 256 + threadIdx.x)) * 4;
  float4 v = *(const float4*)(src + i);
  ushort4 o;
  o.x = f2bf(v.x); o.y = f2bf(v.y); o.z = f2bf(v.z); o.w = f2bf(v.w);
  *(ushort4*)(dst + i) = o;
}

// ---------------- 128x128 bf16 GEMM, C = A * B^T (A:[M][K], B:[N][K]) ------
// MODE 0: write f32 row-major [M][N].  MODE 1: write bf16 to [B,H,S,DK].
template <int MODE>
__global__ __launch_bounds__(256) void gemm128(
    const u16* __restrict__ A, const u16* __restrict__ B0, const u16* __restrict__ B1,
    const u16* __restrict__ B2, void* __restrict__ O0, void* __restrict__ O1,
    void* __restrict__ O2) {
  __shared__ alignas(16) u16 As[128 * 64];
  __shared__ alignas(16) u16 Bs[128 * 64];
  int z = blockIdx.z;
  const u16* Bm = (z == 0) ? B0 : ((z == 1) ? B1 : B2);
  void* Om = (z == 0) ? O0 : ((z == 1) ? O1 : O2);
  int m0 = blockIdx.x * 128, n0 = blockIdx.y * 128;
  int t = threadIdx.x;
  int w = t >> 6, lane = t & 63, lr = lane >> 4, lc = lane & 15;
  int wr = w >> 1, wc = w & 1;
  f32x4 acc[4][4] = {};
  int srow = t >> 3;
  int scolb = (t & 7) * 16;
  const char* Ag = (const char*)A;
  const char* Bg = (const char*)Bm;
  for (int k0 = 0; k0 < DMODEL; k0 += 64) {
#pragma unroll
    for (int i = 0; i < 4; i++) {
      gload16(Ag + ((size_t)(m0 + srow + i * 32) * DMODEL + k0) * 2 + scolb,
              (char*)As + i * 4096 + w * 1024);
      gload16(Bg + ((size_t)(n0 + srow + i * 32) * DMODEL + k0) * 2 + scolb,
              (char*)Bs + i * 4096 + w * 1024);
    }
    __syncthreads();
#pragma unroll
    for (int kk = 0; kk < 2; kk++) {
      bf16x8 af[4], bfr[4];
#pragma unroll
      for (int mi = 0; mi < 4; mi++)
        af[mi] = *(const bf16x8*)(As + (wr * 64 + mi * 16 + lc) * 64 + kk * 32 + lr * 8);
#pragma unroll
      for (int ni = 0; ni < 4; ni++)
        bfr[ni] = *(const bf16x8*)(Bs + (wc * 64 + ni * 16 + lc) * 64 + kk * 32 + lr * 8);
#pragma unroll
      for (int mi = 0; mi < 4; mi++)
#pragma unroll
        for (int ni = 0; ni < 4; ni++)
          acc[mi][ni] =
              __builtin_amdgcn_mfma_f32_16x16x32_bf16(af[mi], bfr[ni], acc[mi][ni], 0, 0, 0);
    }
    __syncthreads();
  }
  if (MODE == 0) {
    float* Of = (float*)Om;
#pragma unroll
    for (int mi = 0; mi < 4; mi++)
#pragma unroll
      for (int ni = 0; ni < 4; ni++) {
        int m = m0 + wr * 64 + mi * 16 + lr * 4;
        int n = n0 + wc * 64 + ni * 16 + lc;
#pragma unroll
        for (int r = 0; r < 4; r++) Of[(size_t)(m + r) * DMODEL + n] = acc[mi][ni][r];
      }
  } else {
    u16* Oh = (u16*)Om;
#pragma unroll
    for (int mi = 0; mi < 4; mi++)
#pragma unroll
      for (int ni = 0; ni < 4; ni++) {
        int n = n0 + wc * 64 + ni * 16 + lc;
        int h = n >> 6, d = n & 63;
#pragma unroll
        for (int r = 0; r < 4; r++) {
          int m = m0 + wr * 64 + mi * 16 + lr * 4 + r;
          int b = m >> 11, s = m & 2047;
          Oh[((size_t)(b * NHEADS + h) * S_LEN + s) * DHEAD + d] = f2bf(acc[mi][ni][r]);
        }
      }
  }
}

// ---------------- RoPE in-place on bf16 Q (y=0, with 1/8 scale) and K (y=1) -
__global__ __launch_bounds__(256) void rope_k(u16* __restrict__ Q, u16* __restrict__ K,
                                              const int* __restrict__ pos) {
  int sel = blockIdx.y;
  u16* Aq = sel ? K : Q;
  float oscale = sel ? 1.0f : 0.125f;  // fold 1/sqrt(DK) into Q (exact pow2 in bf16)
  int idx = blockIdx.x * 256 + threadIdx.x;  // 0..262143 (B*H*S*4)
  int r = idx >> 2, seg = idx & 3;
  int b = r >> 15, s = r & 2047;
  float p = (float)pos[(b << 11) + s];
  u16* ptr = Aq + (size_t)r * DHEAD + seg * 16;
  alignas(16) u16 e[16];
  *(uint4*)&e[0] = *(const uint4*)ptr;
  *(uint4*)&e[8] = *(const uint4*)(ptr + 8);
#pragma unroll
  for (int j = 0; j < 8; j++) {
    int i = seg * 8 + j;  // pair index 0..31
    float fr = exp2f(-0.4152410118407687f * (float)i);  // theta^(-2i/64)
    float ang = p * fr;
    float sn, cs;
    __sincosf(ang, &sn, &cs);
    float ev = bf2f(e[2 * j]), ov = bf2f(e[2 * j + 1]);
    e[2 * j] = f2bf((ev * cs - ov * sn) * oscale);
    e[2 * j + 1] = f2bf((ev * sn + ov * cs) * oscale);
  }
  *(uint4*)ptr = *(const uint4*)&e[0];
  *(uint4*)(ptr + 8) = *(const uint4*)&e[8];
}

// ---------------- V [B,H,S,DK] -> VT [B,H,DK,S] -----------------------------
__global__ __launch_bounds__(256) void transpose_v(const u16* __restrict__ V,
                                                   u16* __restrict__ VT) {
  __shared__ alignas(16) u16 T[64][72];
  int kv0 = blockIdx.x * 64;
  int bh = blockIdx.y;
  int t = threadIdx.x;
  int rr = t >> 3, c8 = (t & 7) * 8;
  const u16* src = V + ((size_t)bh * S_LEN + kv0) * DHEAD;
#pragma unroll
  for (int i = 0; i < 2; i++) {
    const u16* sp = src + (size_t)(rr + i * 32) * DHEAD + c8;
    *(uint2*)&T[rr + i * 32][c8] = *(const uint2*)sp;
    *(uint2*)&T[rr + i * 32][c8 + 4] = *(const uint2*)(sp + 4);
  }
  __syncthreads();
  u16* dst = VT + (size_t)bh * DHEAD * S_LEN + kv0;
#pragma unroll
  for (int i = 0; i < 2; i++) {
    int d = rr + i * 32;
    ushort4 a, c;
    a.x = T[c8 + 0][d]; a.y = T[c8 + 1][d]; a.z = T[c8 + 2][d]; a.w = T[c8 + 3][d];
    c.x = T[c8 + 4][d]; c.y = T[c8 + 5][d]; c.z = T[c8 + 6][d]; c.w = T[c8 + 7][d];
    *(ushort4*)(dst + (size_t)d * S_LEN + c8) = a;
    *(ushort4*)(dst + (size_t)d * S_LEN + c8 + 4) = c;
  }
}

// ---------------- causal flash attention, swapped-QK^T in-register softmax --
// v4: v3 + fixed cross-half reductions (__shfl_xor(…,32) for max/sum — the v3
// in-place permlane asm with duplicated inputs let the compiler coalesce both
// operands into one register, destroying the pair-max -> inf/NaN). P packing
// now via __builtin_amdgcn_permlane32_swap (distinct inputs, both results).
__global__ __launch_bounds__(256) void attn_k(const u16* __restrict__ Q,
                                              const u16* __restrict__ K,
                                              const u16* __restrict__ VT,
                                              u16* __restrict__ O) {
  __shared__ alignas(16) u16 Ks[2][64 * 64];
  __shared__ alignas(16) u16 Vs[2][64 * 64];  // VT tile: [d][kv]
  int bh = blockIdx.x;                        // bh fastest -> bh%8 = XCD
  int qc = 15 - (int)blockIdx.y;              // heavy blocks first
  int t = threadIdx.x, w = t >> 6, lane = t & 63;
  int ql = lane & 31, h = lane >> 5;
  size_t base = (size_t)bh * S_LEN * DHEAD;
  int q0w = qc * 128 + w * 32;
  int qrow = q0w + ql;
  int ntl = (q0w + 31) >> 6;  // this wave's last (diagonal) tile
  int ntmax = 2 * qc + 1;     // block's last tile
  // Q as B-fragments (from global; L2-resident): B[col=q][k = h*8+j] per kt
  bf16x8 qf[4];
#pragma unroll
  for (int kt = 0; kt < 4; kt++)
    qf[kt] = *(const bf16x8*)(Q + base + (size_t)qrow * DHEAD + kt * 16 + h * 8);
  f32x16 oacc[2] = {};        // O^T: [d-tile][16], d = 32*dt + (r&3)+8*(r>>2)+4h, col q
  float mrun = -1e30f, lrun = 0.0f;
  const float L2E = 1.4426950408889634f;
  int srow = t >> 3;
  int swc = ((t & 7) ^ (srow & 7)) << 4;  // pre-swizzled source chunk (bytes)
  const char* Kg0 = (const char*)K + (base + (size_t)srow * DHEAD) * 2 + swc;
  const char* Vg0 = (const char*)VT + (base + (size_t)srow * S_LEN) * 2 + swc;
  char* klb = (char*)&Ks[0][0] + w * 1024;
  char* vlb = (char*)&Vs[0][0] + w * 1024;

#define STAGE(nt, buf)                                          \
  do {                                                          \
    size_t kvo = (size_t)(nt) * 64;                             \
    const char* kg = Kg0 + kvo * DHEAD * 2;                     \
    const char* vg = Vg0 + kvo * 2;                             \
    char* kl = klb + (buf) * 8192;                              \
    char* vl = vlb + (buf) * 8192;                              \
    gload16(kg, kl);                                            \
    gload16(kg + (size_t)32 * DHEAD * 2, kl + 4096);            \
    gload16(vg, vl);                                            \
    gload16(vg + (size_t)32 * S_LEN * 2, vl + 4096);            \
  } while (0)

  STAGE(0, 0);
  asm volatile("s_waitcnt vmcnt(0)" ::: "memory");
  __builtin_amdgcn_s_barrier();
  asm volatile("" ::: "memory");
  int cur = 0;
  int swz = (ql & 7);  // row&7 is the same for kv rows q, 32+q and d rows
  for (int nt = 0; nt <= ntmax; nt++) {
    if (nt < ntmax) STAGE(nt + 1, cur ^ 1);
    if (nt <= ntl) {
      const char* kb = (const char*)&Ks[cur][0];
      const char* vb = (const char*)&Vs[cur][0];
      // S^T = K * Q^T : A-frag rows = kv, B-frag cols = q
      f32x16 sacc[2] = {};
      __builtin_amdgcn_s_setprio(1);
#pragma unroll
      for (int kt = 0; kt < 4; kt++) {
        int c = ((2 * kt + h) ^ swz) << 4;
        bf16x8 k0 = *(const bf16x8*)(kb + ql * 128 + c);
        bf16x8 k1 = *(const bf16x8*)(kb + (32 + ql) * 128 + c);
        sacc[0] = MFMA32(k0, qf[kt], sacc[0]);
        sacc[1] = MFMA32(k1, qf[kt], sacc[1]);
      }
      __builtin_amdgcn_s_setprio(0);
      if (nt == ntl) {  // causal mask on the diagonal tile
#pragma unroll
        for (int r = 0; r < 16; r++) {
          int kvb = nt * 64 + (r & 3) + 8 * (r >> 2) + 4 * h;
          if (kvb > qrow) sacc[0][r] = -1e30f;
          if (kvb + 32 > qrow) sacc[1][r] = -1e30f;
        }
      }
      // row max: in-register tree over own 32 values + cross-half shfl
      float t8[8];
#pragma unroll
      for (int r = 0; r < 8; r++)
        t8[r] = fmaxf(fmaxf(sacc[0][r], sacc[0][r + 8]), fmaxf(sacc[1][r], sacc[1][r + 8]));
      float t4a = fmaxf(t8[0], t8[4]), t4b = fmaxf(t8[1], t8[5]);
      float t4c = fmaxf(t8[2], t8[6]), t4d = fmaxf(t8[3], t8[7]);
      float mx = fmaxf(fmaxf(t4a, t4b), fmaxf(t4c, t4d));
      mx = fmaxf(mx, __shfl_xor(mx, 32));  // combine halves (lanes l <-> l+32)
      // defer-max: only rescale when max grew by > 8*ln2 (P bounded by 2^8)
      bool up = mx > mrun + 5.5451774444795624f;
      if (__any(up)) {
        float newm = up ? mx : mrun;
        float scl = exp2f((mrun - newm) * L2E);
        mrun = newm;
        lrun *= scl;
#pragma unroll
        for (int r = 0; r < 16; r++) { oacc[0][r] *= scl; oacc[1][r] *= scl; }
      }
      // p = exp2((s - m)*log2e) via fma
      float nm2 = -mrun * L2E;
#pragma unroll
      for (int r = 0; r < 16; r++) {
        sacc[0][r] = exp2f(__builtin_fmaf(sacc[0][r], L2E, nm2));
        sacc[1][r] = exp2f(__builtin_fmaf(sacc[1][r], L2E, nm2));
      }
      // row-sum partial (own 32 kv; cross-half combined once at the end)
      float u8[8];
#pragma unroll
      for (int r = 0; r < 8; r++)
        u8[r] = (sacc[0][r] + sacc[0][r + 8]) + (sacc[1][r] + sacc[1][r + 8]);
      lrun += ((u8[0] + u8[4]) + (u8[1] + u8[5])) + ((u8[2] + u8[6]) + (u8[3] + u8[7]));
      // P^T -> bf16 B-frags (verified mapping: r0 -> word0, r1 -> word2)
      u32x4 pa[4];
#pragma unroll
      for (int tau = 0; tau < 2; tau++) {
        u32x2 rA = plswap2(cvtpk(sacc[tau][0], sacc[tau][1]),
                           cvtpk(sacc[tau][4], sacc[tau][5]));
        pa[2 * tau][0] = rA[0]; pa[2 * tau][2] = rA[1];
        u32x2 rC = plswap2(cvtpk(sacc[tau][2], sacc[tau][3]),
                           cvtpk(sacc[tau][6], sacc[tau][7]));
        pa[2 * tau][1] = rC[0]; pa[2 * tau][3] = rC[1];
        u32x2 rA1 = plswap2(cvtpk(sacc[tau][8], sacc[tau][9]),
                            cvtpk(sacc[tau][12], sacc[tau][13]));
        pa[2 * tau + 1][0] = rA1[0]; pa[2 * tau + 1][2] = rA1[1];
        u32x2 rC1 = plswap2(cvtpk(sacc[tau][10], sacc[tau][11]),
                            cvtpk(sacc[tau][14], sacc[tau][15]));
        pa[2 * tau + 1][1] = rC1[0]; pa[2 * tau + 1][3] = rC1[1];
      }
      // O^T += V^T * P^T
      __builtin_amdgcn_s_setprio(1);
#pragma unroll
      for (int kt = 0; kt < 4; kt++) {
        int c = ((2 * kt + h) ^ swz) << 4;
        bf16x8 v0 = *(const bf16x8*)(vb + ql * 128 + c);
        bf16x8 v1 = *(const bf16x8*)(vb + (32 + ql) * 128 + c);
        bf16x8 pb = __builtin_bit_cast(bf16x8, pa[kt]);
        oacc[0] = MFMA32(v0, pb, oacc[0]);
        oacc[1] = MFMA32(v1, pb, oacc[1]);
      }
      __builtin_amdgcn_s_setprio(0);
    }
    asm volatile("s_waitcnt vmcnt(0)" ::: "memory");  // next tile's loads landed
    __builtin_amdgcn_s_barrier();
    asm volatile("" ::: "memory");
    cur ^= 1;
  }
#undef STAGE
  // combine cross-half row-sum, normalize, write
  float lsum = lrun + __shfl_xor(lrun, 32);
  float inv = 1.0f / lsum;
  int b = bh >> 4, hd = bh & 15;
  u16* Orow = O + ((size_t)(b * S_LEN + qrow)) * DMODEL + hd * 64;
#pragma unroll
  for (int dt = 0; dt < 2; dt++)
#pragma unroll
    for (int r = 0; r < 16; r++) {
      int d = 32 * dt + (r & 3) + 8 * (r >> 2) + 4 * h;
      Orow[d] = f2bf(oacc[dt][r] * inv);
    }
}

// ---------------- launch -----------------------------------------------------
extern "C" void kernel_launch(void* const* d_in, const int* in_sizes, int n_in,
                              void* d_out, int out_size, void* d_ws, size_t ws_size,
                              hipStream_t stream) {
  (void)in_sizes; (void)n_in; (void)out_size; (void)ws_size;
  const float* x = (const float*)d_in[0];
  const int* tpos = (const int*)d_in[1];
  const float* Wq = (const float*)d_in[2];
  const float* Wk = (const float*)d_in[3];
  const float* Wv = (const float*)d_in[4];
  const float* Wo = (const float*)d_in[5];
  char* ws = (char*)d_ws;
  // workspace map (56 MB total)
  u16* xb  = (u16*)(ws + ((size_t)0 << 20));   // 8 MB  [4096][1024] bf16
  u16* wqb = (u16*)(ws + ((size_t)8 << 20));   // 2 MB
  u16* wkb = (u16*)(ws + ((size_t)10 << 20));  // 2 MB
  u16* wvb = (u16*)(ws + ((size_t)12 << 20));  // 2 MB
  u16* wob = (u16*)(ws + ((size_t)14 << 20));  // 2 MB
  u16* Qb  = (u16*)(ws + ((size_t)16 << 20));  // 8 MB  [B,H,S,DK]
  u16* Kb  = (u16*)(ws + ((size_t)24 << 20));  // 8 MB
  u16* Vb  = (u16*)(ws + ((size_t)32 << 20));  // 8 MB
  u16* VTb = (u16*)(ws + ((size_t)40 << 20));  // 8 MB  [B,H,DK,S]
  u16* Ob  = (u16*)(ws + ((size_t)48 << 20));  // 8 MB  [B,S,DMODEL] bf16

  convert_k<<<dim3(1024, 8), 256, 0, stream>>>(x, Wq, Wk, Wv, Wo, xb, wqb, wkb, wvb, wob);
  gemm128<1><<<dim3(32, 8, 3), 256, 0, stream>>>(xb, wqb, wkb, wvb,
                                                 (void*)Qb, (void*)Kb, (void*)Vb);
  rope_k<<<dim3(1024, 2), 256, 0, stream>>>(Qb, Kb, tpos);
  transpose_v<<<dim3(32, 32), 256, 0, stream>>>(Vb, VTb);
  attn_k<<<dim3(32, 16), 256, 0, stream>>>(Qb, Kb, VTb, Ob);
  gemm128<0><<<dim3(32, 8, 1), 256, 0, stream>>>(Ob, wob, wob, wob, d_out, d_out, d_out);
}